// Round 7
// baseline (117.311 us; speedup 1.0000x reference)
//
#include <hip/hip_runtime.h>
#include <math.h>

// Problem constants
#define BH 2
#define HH 96
#define WW 96
#define NPIX (BH*HH*WW)

// Attention tile geometry: 8x4 pixels, halo 14x10 = 140
#define TH 8
#define TW 4
#define NH 140

typedef __attribute__((ext_vector_type(8))) short short8;
typedef __attribute__((ext_vector_type(4))) float f32x4;

__device__ __forceinline__ unsigned short f2bf(float f) {
    union { float f; unsigned u; } a; a.f = f;
    return (unsigned short)((a.u + 0x7FFFu + ((a.u >> 16) & 1u)) >> 16);
}
__device__ __forceinline__ unsigned packbf(float lo, float hi) {
    return (unsigned)f2bf(lo) | ((unsigned)f2bf(hi) << 16);
}

// ---------------------------------------------------------------------------
// Dispatch 1: q/k proj + WvT. X A-frag loads issued BEFORE W staging so their
// HBM latency hides under the staging + barrier (T14 issue-early).
// ---------------------------------------------------------------------------
#define WT_STRIDE 136   // u16, 16B-aligned rows

__global__ __launch_bounds__(256) void prep_proj_kernel(
    const float* __restrict__ Qg, const float* __restrict__ Kg,
    const float* __restrict__ Wq, const float* __restrict__ bq,
    const float* __restrict__ Wk, const float* __restrict__ bk,
    const float* __restrict__ Wv,
    unsigned short* __restrict__ q_bf, unsigned short* __restrict__ k_bf,
    unsigned short* __restrict__ WvT)
{
    __shared__ unsigned short WT[64 * WT_STRIDE];   // 17.4 KB
    const int bid = blockIdx.x;
    const int tid = threadIdx.x;

    if (bid < 576) {
        const bool isq = bid < 288;
        const float* __restrict__ X   = isq ? Qg : Kg;
        const float* __restrict__ Wt  = isq ? Wq : Wk;
        const float* __restrict__ bia = isq ? bq : bk;
        unsigned short* __restrict__ Y = isq ? q_bf : k_bf;

        const int lane = tid & 63;
        const int wvv  = tid >> 6;
        const int row0 = ((bid % 288) * 4 + wvv) * 16;
        const int qd = lane >> 4, m = lane & 15;

        // (1) issue X loads first (consumed after barrier)
        float4 xa[4][2];
        #pragma unroll
        for (int ks = 0; ks < 4; ++ks) {
            const float4* __restrict__ src = reinterpret_cast<const float4*>(
                X + (size_t)(row0 + m) * 128 + ks * 32 + qd * 8);
            xa[ks][0] = src[0];
            xa[ks][1] = src[1];
        }

        // (2) stage W[128][64] fp32 -> WT[64][128] bf16 (transposed)
        {
            const float4* __restrict__ W4 = reinterpret_cast<const float4*>(Wt);
            #pragma unroll
            for (int i = 0; i < 8; ++i) {
                const int e  = tid + 256 * i;     // float4 idx 0..2047
                const int k  = e >> 4;            // 0..127
                const int n4 = (e & 15) * 4;      // 0..60
                const float4 v = W4[e];
                WT[(n4 + 0) * WT_STRIDE + k] = f2bf(v.x);
                WT[(n4 + 1) * WT_STRIDE + k] = f2bf(v.y);
                WT[(n4 + 2) * WT_STRIDE + k] = f2bf(v.z);
                WT[(n4 + 3) * WT_STRIDE + k] = f2bf(v.w);
            }
        }
        __syncthreads();

        short8 afr[4];
        #pragma unroll
        for (int ks = 0; ks < 4; ++ks) {
            const float4 a0 = xa[ks][0], a1 = xa[ks][1];
            short8 f;
            f[0] = (short)f2bf(a0.x); f[1] = (short)f2bf(a0.y);
            f[2] = (short)f2bf(a0.z); f[3] = (short)f2bf(a0.w);
            f[4] = (short)f2bf(a1.x); f[5] = (short)f2bf(a1.y);
            f[6] = (short)f2bf(a1.z); f[7] = (short)f2bf(a1.w);
            afr[ks] = f;
        }

        #pragma unroll
        for (int n = 0; n < 4; ++n) {
            f32x4 acc = {};
            #pragma unroll
            for (int ks = 0; ks < 4; ++ks) {
                const short8 bfr = *reinterpret_cast<const short8*>(
                    &WT[(n * 16 + m) * WT_STRIDE + ks * 32 + qd * 8]);
                acc = __builtin_amdgcn_mfma_f32_16x16x32_bf16(afr[ks], bfr, acc, 0, 0, 0);
            }
            const int col = n * 16 + m;
            const float bb = bia[col];
            #pragma unroll
            for (int r = 0; r < 4; ++r)
                Y[(size_t)(row0 + qd * 4 + r) * 64 + col] = f2bf(acc[r] + bb);
        }
    } else {
        const int base = (bid - 576) * 1024 + tid * 4;
        #pragma unroll
        for (int i = 0; i < 4; ++i) {
            const int e = base + i;                        // e = n*128 + k
            WvT[e] = f2bf(Wv[(e & 127) * 128 + (e >> 7)]);
        }
    }
}

// ---------------------------------------------------------------------------
// Dispatch 2: neighborhood attention + out-projection.
// Round-6 load order (qa -> kb -> V-to-regs -> scores -> ... -> V ds_write)
// with COMPACT LDS for 3 blocks/CU (46.6 KB <= 53.3 KB):
//  - vlds[128][144] (P cols >=144 are structurally zero: pa[4] zeroed for
//    qd>=2, B-read clamped; staging skips pb>=18; swizzle blocks 16/17 XOR f&1)
//  - ng=3 waves own only tile 8 (tile 9 fully out-of-halo -> zero)
//  - PS[32][152], softmax partials live in the 8-u16 row pad (cols 144..151)
//  - AS[32][136] ALIASES PS: pa[] is register-resident, barrier B1.5 after pa
//    loads guarantees all P reads complete before AS writes.
//  - __launch_bounds__(512,6): VGPR<=84 so 3 blocks/CU are resident.
// LDS (u16): PS[32][152] @0 (AS aliases) | vlds[128][144] @4864
//   -> 23296 u16 = 46592 B. 3 barriers.
// ---------------------------------------------------------------------------
#define PS_OFF 0
#define PS_STRIDE 152
#define SMPAD 144
#define AS_OFF 0
#define AS_STRIDE 136
#define V_OFF 4864
#define VS 144          // u16 stride: 288 B rows
#define LDS_N 23296

__global__ __launch_bounds__(512, 6) void attn_kernel(
    const unsigned short* __restrict__ q_bf, const unsigned short* __restrict__ k_bf,
    const float* __restrict__ V, const unsigned short* __restrict__ WvT,
    const float* __restrict__ bv, float* __restrict__ out)
{
    __shared__ unsigned short lds[LDS_N];
    const int tid  = threadIdx.x;
    const int lane = tid & 63;
    const int wv   = tid >> 6;     // 0..7
    const int mt   = wv & 1;
    const int ng   = wv >> 1;      // 0..3

    const int bid  = blockIdx.x;   // 576
    const int bimg = bid / 288;
    const int tidx = bid % 288;
    const int ty = tidx / 24, tx = tidx % 24;
    const int y0 = ty * TH, x0 = tx * TW;

    const int qd = lane >> 4, m = lane & 15;

    // tiles 0..8: ng0:{0,1,2} ng1:{3,4,5} ng2:{6,7} ng3:{8}
    const int ntbase = (ng < 2) ? ng * 3 : 6 + (ng - 2) * 2;
    const int ntcnt  = (ng < 2) ? 3 : ((ng == 2) ? 2 : 1);

    // ---- (1) q A-frags: first loads issued ----
    short8 qa[2];
    {
        const int py = mt * 4 + (m >> 2), px = m & 3;
        const size_t gq = (size_t)(bimg * HH + y0 + py) * WW + (x0 + px);
        #pragma unroll
        for (int ks = 0; ks < 2; ++ks)
            qa[ks] = *reinterpret_cast<const short8*>(q_bf + gq * 64 + ks * 32 + qd * 8);
    }

    // ---- (2) k score-gather B-frags into regs ----
    short8 kb[3][2];
    #pragma unroll
    for (int n5 = 0; n5 < 3; ++n5) {
        if (n5 >= ntcnt) break;
        const int h  = (ntbase + n5) * 16 + m;
        const int hy = (h * 6554) >> 16;
        const int hx = h - hy * 10;
        const int iy = y0 - 3 + hy, ix = x0 - 3 + hx;
        const bool ok = ((unsigned)iy < HH) & ((unsigned)ix < WW) & (h < NH);
        const size_t ob = ok ? (size_t)((bimg * HH + iy) * WW + ix) * 64 : 0;
        #pragma unroll
        for (int ks = 0; ks < 2; ++ks)
            kb[n5][ks] = *reinterpret_cast<const short8*>(k_bf + ob + ks * 32 + qd * 8);
    }

    // ---- (3) V halo loads into REGISTERS (consumed at stage-write pre-B1) ----
    const int q4  = tid & 31;          // ch-quad
    const int pp0 = tid >> 5;          // pixel-pair slot 0..15
    float4 va[5], vb[5];
    #pragma unroll
    for (int rnd = 0; rnd < 5; ++rnd) {
        if (rnd == 4 && pp0 >= 8) break;   // pb 18,19 not stored
        const int pp  = rnd * 16 + pp0;    // pair 0..79
        const int p0p = pp * 2;
        int o0, o1;
        {
            const int hy = (p0p * 6554) >> 16;  // p/10
            const int hx = p0p - hy * 10;
            const int iy = y0 - 3 + hy, ix = x0 - 3 + hx;
            const bool ok = ((unsigned)iy < HH) & ((unsigned)ix < WW) & (p0p < NH);
            o0 = ok ? ((bimg * HH + iy) * WW + ix) : 0;
        }
        {
            const int p1p = p0p + 1;
            const int hy = (p1p * 6554) >> 16;
            const int hx = p1p - hy * 10;
            const int iy = y0 - 3 + hy, ix = x0 - 3 + hx;
            const bool ok = ((unsigned)iy < HH) & ((unsigned)ix < WW) & (p1p < NH);
            o1 = ok ? ((bimg * HH + iy) * WW + ix) : 0;
        }
        va[rnd] = *reinterpret_cast<const float4*>(V + (size_t)o0 * 128 + q4 * 4);
        vb[rnd] = *reinterpret_cast<const float4*>(V + (size_t)o1 * 128 + q4 * 4);
    }

    // ---- (4) scores: waits only on qa+kb; V loads remain outstanding ----
    f32x4 sc[3];
    #pragma unroll
    for (int n5 = 0; n5 < 3; ++n5) {
        if (n5 >= ntcnt) break;
        f32x4 a = {};
        #pragma unroll
        for (int ks = 0; ks < 2; ++ks)
            a = __builtin_amdgcn_mfma_f32_16x16x32_bf16(qa[ks], kb[n5][ks], a, 0, 0, 0);
        sc[n5] = a;
    }

    // ---- (5) mask + exp (no max) + P-write + partial sums ----
    float sm[4] = {0.f, 0.f, 0.f, 0.f};
    #pragma unroll
    for (int n5 = 0; n5 < 3; ++n5) {
        if (n5 >= ntcnt) break;
        const int h  = (ntbase + n5) * 16 + m;
        const int hy = (h * 6554) >> 16;
        const int hx = h - hy * 10;
        const int iy = y0 - 3 + hy, ix = x0 - 3 + hx;
        const bool imgok = ((unsigned)iy < HH) & ((unsigned)ix < WW) & (h < NH);
        const int py = mt * 4 + qd;
        const int col = (ntbase + n5) * 16 + m;
        #pragma unroll
        for (int r = 0; r < 4; ++r) {
            const bool ok = imgok & ((unsigned)(hy - py) <= 6u) & ((unsigned)(hx - r) <= 6u);
            const float e = ok ? __expf(sc[n5][r] * 0.125f) : 0.f;
            sm[r] += e;
            const int row = mt * 16 + qd * 4 + r;
            lds[PS_OFF + row * PS_STRIDE + col] = f2bf(e);
        }
    }
    #pragma unroll
    for (int r = 0; r < 4; ++r)
        #pragma unroll
        for (int off = 1; off < 16; off <<= 1)
            sm[r] += __shfl_xor(sm[r], off);

    if (m == 0) {
        #pragma unroll
        for (int r = 0; r < 4; ++r) {
            const int row = mt * 16 + qd * 4 + r;
            *reinterpret_cast<float*>(&lds[PS_OFF + row * PS_STRIDE + SMPAD + ng * 2]) = sm[r];
        }
    }

    // ---- (6) V convert + ds_write (waits V loads; latency spent in 4-5) ----
    {
        const int fsw = (q4 >> 1) & 7;
        unsigned* __restrict__ vl32 = reinterpret_cast<unsigned*>(&lds[V_OFF]);
        #pragma unroll
        for (int rnd = 0; rnd < 5; ++rnd) {
            if (rnd == 4 && pp0 >= 8) break;
            const int pp   = rnd * 16 + pp0;
            const int pb   = rnd * 4 + (pp0 >> 2);                     // p>>3, 0..17
            const int sb   = pb ^ ((pb < 16) ? fsw : (fsw & 1));       // swizzled block
            const int colw = sb * 4 + (pp & 3);                        // b32 col
            const int rb   = q4 * 4;
            vl32[(rb + 0) * (VS / 2) + colw] = packbf(va[rnd].x, vb[rnd].x);
            vl32[(rb + 1) * (VS / 2) + colw] = packbf(va[rnd].y, vb[rnd].y);
            vl32[(rb + 2) * (VS / 2) + colw] = packbf(va[rnd].z, vb[rnd].z);
            vl32[(rb + 3) * (VS / 2) + colw] = packbf(va[rnd].w, vb[rnd].w);
        }
    }
    __syncthreads();   // B1: P + sum partials + vlds ready

    // ---- merge 4-way sums -> fac = 1/S per output row (reads SM pad) ----
    float fac[4];
    #pragma unroll
    for (int r = 0; r < 4; ++r) {
        const int row = mt * 16 + qd * 4 + r;
        const float* __restrict__ sp =
            reinterpret_cast<const float*>(&lds[PS_OFF + row * PS_STRIDE + SMPAD]);
        fac[r] = 1.0f / (sp[0] + sp[1] + sp[2] + sp[3]);
    }

    // ---- prefetch WvT B-frags (L2 latency hides under PV) ----
    short8 wf[2][4];
    #pragma unroll
    for (int n2 = 0; n2 < 2; ++n2)
        #pragma unroll
        for (int ks = 0; ks < 4; ++ks)
            wf[n2][ks] = *reinterpret_cast<const short8*>(
                WvT + ((ng * 2 + n2) * 16 + m) * 128 + ks * 32 + qd * 8);

    // ---- P A-frags to regs (ks=4: cols 128..143 only; qd>=2 zeroed) ----
    short8 pa[5];
    #pragma unroll
    for (int ks = 0; ks < 4; ++ks)
        pa[ks] = *reinterpret_cast<const short8*>(
            &lds[PS_OFF + (mt * 16 + m) * PS_STRIDE + ks * 32 + qd * 8]);
    {
        short8 z = {};
        pa[4] = z;
        if (qd < 2)
            pa[4] = *reinterpret_cast<const short8*>(
                &lds[PS_OFF + (mt * 16 + m) * PS_STRIDE + 128 + qd * 8]);
    }
    __syncthreads();   // B1.5: all P reads done -> AS may alias PS

    // ---- PV: A = pa regs, B = vlds[ch][p] swizzled b128 ----
    f32x4 oacc[2] = {};
    #pragma unroll
    for (int ks = 0; ks < 5; ++ks) {
        const int kb2 = ks * 4 + qd;                 // logical 8-px block 0..19
        #pragma unroll
        for (int n2 = 0; n2 < 2; ++n2) {
            const int ch = (ng * 2 + n2) * 16 + m;
            const int f  = (ch >> 3) & 7;
            const int sb = (kb2 < 16) ? (kb2 ^ f) : ((kb2 < 18) ? (kb2 ^ (f & 1)) : 0);
            const short8 bfr = *reinterpret_cast<const short8*>(
                &lds[V_OFF + ch * VS + sb * 8]);
            oacc[n2] = __builtin_amdgcn_mfma_f32_16x16x32_bf16(pa[ks], bfr, oacc[n2], 0, 0, 0);
        }
    }

    // ---- scale by 1/S and write att -> AS (aliases PS) ----
    #pragma unroll
    for (int n2 = 0; n2 < 2; ++n2)
        #pragma unroll
        for (int r = 0; r < 4; ++r) {
            const int row = mt * 16 + qd * 4 + r;
            const int col = (ng * 2 + n2) * 16 + m;
            lds[AS_OFF + row * AS_STRIDE + col] = f2bf(oacc[n2][r] * fac[r]);
        }
    __syncthreads();   // B2: att complete

    // ---- out-proj + bias + relu ----
    short8 aa[4];
    #pragma unroll
    for (int ks = 0; ks < 4; ++ks)
        aa[ks] = *reinterpret_cast<const short8*>(
            &lds[AS_OFF + (mt * 16 + m) * AS_STRIDE + ks * 32 + qd * 8]);

    #pragma unroll
    for (int n2 = 0; n2 < 2; ++n2) {
        const int nt = ng * 2 + n2;
        f32x4 a = {};
        #pragma unroll
        for (int ks = 0; ks < 4; ++ks)
            a = __builtin_amdgcn_mfma_f32_16x16x32_bf16(aa[ks], wf[n2][ks], a, 0, 0, 0);
        const int col = nt * 16 + m;
        const float bb = bv[col];
        #pragma unroll
        for (int r = 0; r < 4; ++r) {
            const int py = mt * 4 + qd, px = r;
            const size_t gp = (size_t)(bimg * HH + y0 + py) * WW + (x0 + px);
            out[gp * 128 + col] = fmaxf(a[r] + bb, 0.f);
        }
    }
}

extern "C" void kernel_launch(void* const* d_in, const int* in_sizes, int n_in,
                              void* d_out, int out_size, void* d_ws, size_t ws_size,
                              hipStream_t stream)
{
    const float* Q  = (const float*)d_in[0];
    const float* K  = (const float*)d_in[1];
    const float* V  = (const float*)d_in[2];
    const float* Wq = (const float*)d_in[3];
    const float* bq = (const float*)d_in[4];
    const float* Wk = (const float*)d_in[5];
    const float* bk = (const float*)d_in[6];
    const float* Wv = (const float*)d_in[7];
    const float* bv = (const float*)d_in[8];
    float* out = (float*)d_out;

    unsigned short* wbase = (unsigned short*)d_ws;
    unsigned short* WvT   = wbase + 16384;
    unsigned short* q_bf  = wbase + 32768;             // NPIX*64 bf16
    unsigned short* k_bf  = q_bf + (size_t)NPIX * 64;  // NPIX*64 bf16

    prep_proj_kernel<<<592, 256, 0, stream>>>(Q, K, Wq, bq, Wk, bk, Wv,
                                              q_bf, k_bf, WvT);
    attn_kernel<<<576, 512, 0, stream>>>(q_bf, k_bf, V, WvT, bv, out);
}

// Round 8
// 105.663 us; speedup vs baseline: 1.1102x; 1.1102x over previous
//
#include <hip/hip_runtime.h>
#include <math.h>

// Problem constants
#define BH 2
#define HH 96
#define WW 96
#define NPIX (BH*HH*WW)

// Attention tile geometry: 8x4 pixels, halo 14x10 = 140 (pad 160)
#define TH 8
#define TW 4
#define NH 140

typedef __attribute__((ext_vector_type(8))) short short8;
typedef __attribute__((ext_vector_type(4))) float f32x4;

__device__ __forceinline__ unsigned short f2bf(float f) {
    union { float f; unsigned u; } a; a.f = f;
    return (unsigned short)((a.u + 0x7FFFu + ((a.u >> 16) & 1u)) >> 16);
}
__device__ __forceinline__ unsigned packbf(float lo, float hi) {
    return (unsigned)f2bf(lo) | ((unsigned)f2bf(hi) << 16);
}

// ---------------------------------------------------------------------------
// Dispatch 1: q/k proj + WvT (round-4/6 structure, unchanged).
//   blocks 0..287   : q-projection (W staged transposed in LDS, b128 B-frags)
//   blocks 288..575 : k-projection (same)
//   blocks 576..591 : Wv -> WvT [128][128] bf16
// ---------------------------------------------------------------------------
#define WT_STRIDE 136   // u16, 16B-aligned rows

__global__ __launch_bounds__(256) void prep_proj_kernel(
    const float* __restrict__ Qg, const float* __restrict__ Kg,
    const float* __restrict__ Wq, const float* __restrict__ bq,
    const float* __restrict__ Wk, const float* __restrict__ bk,
    const float* __restrict__ Wv,
    unsigned short* __restrict__ q_bf, unsigned short* __restrict__ k_bf,
    unsigned short* __restrict__ WvT)
{
    __shared__ unsigned short WT[64 * WT_STRIDE];   // 17.4 KB
    const int bid = blockIdx.x;
    const int tid = threadIdx.x;

    if (bid < 576) {
        const bool isq = bid < 288;
        const float* __restrict__ X   = isq ? Qg : Kg;
        const float* __restrict__ Wt  = isq ? Wq : Wk;
        const float* __restrict__ bia = isq ? bq : bk;
        unsigned short* __restrict__ Y = isq ? q_bf : k_bf;

        // stage W[128][64] fp32 -> WT[64][128] bf16 (transposed), coalesced
        {
            const float4* __restrict__ W4 = reinterpret_cast<const float4*>(Wt);
            #pragma unroll
            for (int i = 0; i < 8; ++i) {
                const int e  = tid + 256 * i;     // float4 idx 0..2047
                const int k  = e >> 4;            // 0..127
                const int n4 = (e & 15) * 4;      // 0..60
                const float4 v = W4[e];
                WT[(n4 + 0) * WT_STRIDE + k] = f2bf(v.x);
                WT[(n4 + 1) * WT_STRIDE + k] = f2bf(v.y);
                WT[(n4 + 2) * WT_STRIDE + k] = f2bf(v.z);
                WT[(n4 + 3) * WT_STRIDE + k] = f2bf(v.w);
            }
        }
        __syncthreads();

        const int lane = tid & 63;
        const int wvv  = tid >> 6;
        const int row0 = ((bid % 288) * 4 + wvv) * 16;
        const int qd = lane >> 4, m = lane & 15;

        short8 afr[4];
        #pragma unroll
        for (int ks = 0; ks < 4; ++ks) {
            const float4* __restrict__ src = reinterpret_cast<const float4*>(
                X + (size_t)(row0 + m) * 128 + ks * 32 + qd * 8);
            const float4 a0 = src[0], a1 = src[1];
            short8 f;
            f[0] = (short)f2bf(a0.x); f[1] = (short)f2bf(a0.y);
            f[2] = (short)f2bf(a0.z); f[3] = (short)f2bf(a0.w);
            f[4] = (short)f2bf(a1.x); f[5] = (short)f2bf(a1.y);
            f[6] = (short)f2bf(a1.z); f[7] = (short)f2bf(a1.w);
            afr[ks] = f;
        }

        #pragma unroll
        for (int n = 0; n < 4; ++n) {
            f32x4 acc = {};
            #pragma unroll
            for (int ks = 0; ks < 4; ++ks) {
                const short8 bfr = *reinterpret_cast<const short8*>(
                    &WT[(n * 16 + m) * WT_STRIDE + ks * 32 + qd * 8]);
                acc = __builtin_amdgcn_mfma_f32_16x16x32_bf16(afr[ks], bfr, acc, 0, 0, 0);
            }
            const int col = n * 16 + m;
            const float bb = bia[col];
            #pragma unroll
            for (int r = 0; r < 4; ++r)
                Y[(size_t)(row0 + qd * 4 + r) * 64 + col] = f2bf(acc[r] + bb);
        }
    } else {
        const int base = (bid - 576) * 1024 + tid * 4;
        #pragma unroll
        for (int i = 0; i < 4; ++i) {
            const int e = base + i;                        // e = n*128 + k
            WvT[e] = f2bf(Wv[(e & 127) * 128 + (e >> 7)]);
        }
    }
}

// ---------------------------------------------------------------------------
// Dispatch 2: neighborhood attention + out-projection (round-6 structure +
// XCD-AWARE BLOCK SWIZZLE). wgid = (bid%8)*72 + bid/8 (576%8==0, bijective):
// each XCD owns 72 contiguous tiles (3 tile-rows), so neighboring tiles'
// overlapping V halos (4.4x re-read) and k_bf gathers hit the XCD-local L2
// instead of crossing to L3/HBM — attacks the V-wait latency on the critical
// path. Load order: qa -> kb gathers -> V halo to REGISTERS -> scores (V
// stays outstanding) -> softmax/P-write -> V convert+ds_write (T14 split).
// NO-MAX softmax, unnormalized P, 1/S folded into PV output. 2 barriers.
// LDS (u16): PS[32][168] @0 | AS[32][136] @5376 | SM 128f @9728 |
//            vlds[128][160] @10240 -> 30720 u16 = 61440 B (2 blk/CU).
// ---------------------------------------------------------------------------
#define PS_OFF 0
#define PS_STRIDE 168
#define AS_OFF 5376
#define AS_STRIDE 136
#define SM_OFF 9728
#define V_OFF 10240
#define VS 160          // u16 stride: 320 B rows
#define LDS_N 30720

__global__ __launch_bounds__(512, 4) void attn_kernel(
    const unsigned short* __restrict__ q_bf, const unsigned short* __restrict__ k_bf,
    const float* __restrict__ V, const unsigned short* __restrict__ WvT,
    const float* __restrict__ bv, float* __restrict__ out)
{
    __shared__ unsigned short lds[LDS_N];
    const int tid  = threadIdx.x;
    const int lane = tid & 63;
    const int wv   = tid >> 6;     // 0..7
    const int mt   = wv & 1;
    const int ng   = wv >> 1;      // 0..3

    // XCD-aware swizzle: XCD k (= blockIdx.x % 8) handles tiles [k*72,(k+1)*72)
    const int bid  = (blockIdx.x & 7) * 72 + (blockIdx.x >> 3);   // 576 blocks
    const int bimg = bid / 288;
    const int tidx = bid % 288;
    const int ty = tidx / 24, tx = tidx % 24;
    const int y0 = ty * TH, x0 = tx * TW;

    const int qd = lane >> 4, m = lane & 15;

    float* __restrict__ smf = reinterpret_cast<float*>(&lds[SM_OFF]);

    const int ntbase = (ng < 2) ? ng * 3 : 6 + (ng - 2) * 2;
    const int ntcnt  = (ng < 2) ? 3 : 2;

    // ---- (1) q A-frags: first loads issued ----
    short8 qa[2];
    {
        const int py = mt * 4 + (m >> 2), px = m & 3;
        const size_t gq = (size_t)(bimg * HH + y0 + py) * WW + (x0 + px);
        #pragma unroll
        for (int ks = 0; ks < 2; ++ks)
            qa[ks] = *reinterpret_cast<const short8*>(q_bf + gq * 64 + ks * 32 + qd * 8);
    }

    // ---- (2) k score-gather B-frags into regs ----
    short8 kb[3][2];
    #pragma unroll
    for (int n5 = 0; n5 < 3; ++n5) {
        if (n5 >= ntcnt) break;
        const int h  = (ntbase + n5) * 16 + m;
        const int hy = (h * 6554) >> 16;
        const int hx = h - hy * 10;
        const int iy = y0 - 3 + hy, ix = x0 - 3 + hx;
        const bool ok = ((unsigned)iy < HH) & ((unsigned)ix < WW) & (h < NH);
        const size_t ob = ok ? (size_t)((bimg * HH + iy) * WW + ix) * 64 : 0;
        #pragma unroll
        for (int ks = 0; ks < 2; ++ks)
            kb[n5][ks] = *reinterpret_cast<const short8*>(k_bf + ob + ks * 32 + qd * 8);
    }

    // ---- (3) V halo loads into REGISTERS (latency-tolerant; consumed at
    //      stage-write just before B1) ----
    const int q4  = tid & 31;          // ch-quad
    const int pp0 = tid >> 5;          // pixel-pair slot 0..15
    float4 va[5], vb[5];
    #pragma unroll
    for (int rnd = 0; rnd < 5; ++rnd) {
        const int pp  = rnd * 16 + pp0;   // pair 0..79
        const int p0p = pp * 2;
        int o0, o1;
        {
            const int hy = (p0p * 6554) >> 16;  // p/10
            const int hx = p0p - hy * 10;
            const int iy = y0 - 3 + hy, ix = x0 - 3 + hx;
            const bool ok = ((unsigned)iy < HH) & ((unsigned)ix < WW) & (p0p < NH);
            o0 = ok ? ((bimg * HH + iy) * WW + ix) : 0;
        }
        {
            const int p1p = p0p + 1;
            const int hy = (p1p * 6554) >> 16;
            const int hx = p1p - hy * 10;
            const int iy = y0 - 3 + hy, ix = x0 - 3 + hx;
            const bool ok = ((unsigned)iy < HH) & ((unsigned)ix < WW) & (p1p < NH);
            o1 = ok ? ((bimg * HH + iy) * WW + ix) : 0;
        }
        va[rnd] = *reinterpret_cast<const float4*>(V + (size_t)o0 * 128 + q4 * 4);
        vb[rnd] = *reinterpret_cast<const float4*>(V + (size_t)o1 * 128 + q4 * 4);
    }

    // ---- (4) scores: waits only on qa+kb; V loads remain outstanding ----
    f32x4 sc[3];
    #pragma unroll
    for (int n5 = 0; n5 < 3; ++n5) {
        if (n5 >= ntcnt) break;
        f32x4 a = {};
        #pragma unroll
        for (int ks = 0; ks < 2; ++ks)
            a = __builtin_amdgcn_mfma_f32_16x16x32_bf16(qa[ks], kb[n5][ks], a, 0, 0, 0);
        sc[n5] = a;
    }

    // ---- (5) mask + exp (no max subtraction) + P-write + partial sums ----
    float sm[4] = {0.f, 0.f, 0.f, 0.f};
    #pragma unroll
    for (int n5 = 0; n5 < 3; ++n5) {
        if (n5 >= ntcnt) break;
        const int h  = (ntbase + n5) * 16 + m;
        const int hy = (h * 6554) >> 16;
        const int hx = h - hy * 10;
        const int iy = y0 - 3 + hy, ix = x0 - 3 + hx;
        const bool imgok = ((unsigned)iy < HH) & ((unsigned)ix < WW) & (h < NH);
        const int py = mt * 4 + qd;
        const int col = (ntbase + n5) * 16 + m;
        #pragma unroll
        for (int r = 0; r < 4; ++r) {
            const bool ok = imgok & ((unsigned)(hy - py) <= 6u) & ((unsigned)(hx - r) <= 6u);
            const float e = ok ? __expf(sc[n5][r] * 0.125f) : 0.f;
            sm[r] += e;
            const int row = mt * 16 + qd * 4 + r;
            lds[PS_OFF + row * PS_STRIDE + col] = f2bf(e);
        }
    }
    #pragma unroll
    for (int r = 0; r < 4; ++r)
        #pragma unroll
        for (int off = 1; off < 16; off <<= 1)
            sm[r] += __shfl_xor(sm[r], off);

    if (m == 0) {
        #pragma unroll
        for (int r = 0; r < 4; ++r) {
            const int row = mt * 16 + qd * 4 + r;
            smf[row * 4 + ng] = sm[r];
        }
    }

    // ---- (6) V convert + ds_write (waits V loads; latency spent in 4-5).
    //      vlds[ch][p], 16B-block XOR swizzle, packed b32 writes. ----
    {
        const int fsw = (q4 >> 1) & 7;     // = (ch>>3)&7 for ch = q4*4..q4*4+3
        unsigned* __restrict__ vl32 = reinterpret_cast<unsigned*>(&lds[V_OFF]);
        #pragma unroll
        for (int rnd = 0; rnd < 5; ++rnd) {
            const int pp   = rnd * 16 + pp0;
            const int pb   = rnd * 4 + (pp0 >> 2);                     // p>>3
            const int sb   = pb ^ ((pb < 16) ? fsw : (fsw & 3));       // swizzled block
            const int colw = sb * 4 + (pp & 3);                        // b32 col
            const int rb   = q4 * 4;
            vl32[(rb + 0) * (VS / 2) + colw] = packbf(va[rnd].x, vb[rnd].x);
            vl32[(rb + 1) * (VS / 2) + colw] = packbf(va[rnd].y, vb[rnd].y);
            vl32[(rb + 2) * (VS / 2) + colw] = packbf(va[rnd].z, vb[rnd].z);
            vl32[(rb + 3) * (VS / 2) + colw] = packbf(va[rnd].w, vb[rnd].w);
        }
    }
    __syncthreads();   // B1: P + sum partials + vlds ready

    // ---- merge 4-way sums -> fac = 1/S per output row ----
    float fac[4];
    #pragma unroll
    for (int r = 0; r < 4; ++r) {
        const int row = mt * 16 + qd * 4 + r;
        const float S = smf[row * 4 + 0] + smf[row * 4 + 1]
                      + smf[row * 4 + 2] + smf[row * 4 + 3];
        fac[r] = 1.0f / S;
    }

    // ---- prefetch WvT B-frags (independent; L2 latency hides under PV) ----
    short8 wf[2][4];
    #pragma unroll
    for (int n2 = 0; n2 < 2; ++n2)
        #pragma unroll
        for (int ks = 0; ks < 4; ++ks)
            wf[n2][ks] = *reinterpret_cast<const short8*>(
                WvT + ((ng * 2 + n2) * 16 + m) * 128 + ks * 32 + qd * 8);

    // ---- PV: A = P (LDS b128), B = vlds[ch][p] swizzled b128 ----
    short8 pa[5];
    #pragma unroll
    for (int ks = 0; ks < 5; ++ks)
        pa[ks] = *reinterpret_cast<const short8*>(
            &lds[PS_OFF + (mt * 16 + m) * PS_STRIDE + ks * 32 + qd * 8]);

    f32x4 oacc[2] = {};
    #pragma unroll
    for (int ks = 0; ks < 5; ++ks) {
        const int kb2 = ks * 4 + qd;                 // logical 8-px block
        #pragma unroll
        for (int n2 = 0; n2 < 2; ++n2) {
            const int ch = (ng * 2 + n2) * 16 + m;
            const int f  = (ch >> 3) & 7;
            const int sb = kb2 ^ ((kb2 < 16) ? f : (f & 3));
            const short8 bfr = *reinterpret_cast<const short8*>(
                &lds[V_OFF + ch * VS + sb * 8]);
            oacc[n2] = __builtin_amdgcn_mfma_f32_16x16x32_bf16(pa[ks], bfr, oacc[n2], 0, 0, 0);
        }
    }

    // ---- scale by 1/S and write att -> AS ----
    #pragma unroll
    for (int n2 = 0; n2 < 2; ++n2)
        #pragma unroll
        for (int r = 0; r < 4; ++r) {
            const int row = mt * 16 + qd * 4 + r;
            const int col = (ng * 2 + n2) * 16 + m;
            lds[AS_OFF + row * AS_STRIDE + col] = f2bf(oacc[n2][r] * fac[r]);
        }
    __syncthreads();   // B2: att complete

    // ---- out-proj + bias + relu ----
    short8 aa[4];
    #pragma unroll
    for (int ks = 0; ks < 4; ++ks)
        aa[ks] = *reinterpret_cast<const short8*>(
            &lds[AS_OFF + (mt * 16 + m) * AS_STRIDE + ks * 32 + qd * 8]);

    #pragma unroll
    for (int n2 = 0; n2 < 2; ++n2) {
        const int nt = ng * 2 + n2;
        f32x4 a = {};
        #pragma unroll
        for (int ks = 0; ks < 4; ++ks)
            a = __builtin_amdgcn_mfma_f32_16x16x32_bf16(aa[ks], wf[n2][ks], a, 0, 0, 0);
        const int col = nt * 16 + m;
        const float bb = bv[col];
        #pragma unroll
        for (int r = 0; r < 4; ++r) {
            const int py = mt * 4 + qd, px = r;
            const size_t gp = (size_t)(bimg * HH + y0 + py) * WW + (x0 + px);
            out[gp * 128 + col] = fmaxf(a[r] + bb, 0.f);
        }
    }
}

extern "C" void kernel_launch(void* const* d_in, const int* in_sizes, int n_in,
                              void* d_out, int out_size, void* d_ws, size_t ws_size,
                              hipStream_t stream)
{
    const float* Q  = (const float*)d_in[0];
    const float* K  = (const float*)d_in[1];
    const float* V  = (const float*)d_in[2];
    const float* Wq = (const float*)d_in[3];
    const float* bq = (const float*)d_in[4];
    const float* Wk = (const float*)d_in[5];
    const float* bk = (const float*)d_in[6];
    const float* Wv = (const float*)d_in[7];
    const float* bv = (const float*)d_in[8];
    float* out = (float*)d_out;

    unsigned short* wbase = (unsigned short*)d_ws;
    unsigned short* WvT   = wbase + 16384;
    unsigned short* q_bf  = wbase + 32768;             // NPIX*64 bf16
    unsigned short* k_bf  = q_bf + (size_t)NPIX * 64;  // NPIX*64 bf16

    prep_proj_kernel<<<592, 256, 0, stream>>>(Q, K, Wq, bq, Wk, bk, Wv,
                                              q_bf, k_bf, WvT);
    attn_kernel<<<576, 512, 0, stream>>>(q_bf, k_bf, V, WvT, bv, out);
}